// Round 11
// baseline (1255.701 us; speedup 1.0000x reference)
//
#include <hip/hip_runtime.h>
#include <stdint.h>

#define H_DIM 4096
#define I_DIM 11008
#define T_DIM 4096

typedef int i32x4 __attribute__((ext_vector_type(4)));
typedef const void __attribute__((address_space(1))) gvoid_t;
typedef void __attribute__((address_space(3))) svoid_t;

__device__ __forceinline__ void gload_lds16(const void* gsrc, void* ldst) {
    __builtin_amdgcn_global_load_lds((gvoid_t*)gsrc, (svoid_t*)ldst, 16, 0, 0);
}
__device__ __forceinline__ void wait_vmcnt5() {
    asm volatile("s_waitcnt vmcnt(5)" ::: "memory");
}
__device__ __forceinline__ void wait_vmcnt0() {
    asm volatile("s_waitcnt vmcnt(0)" ::: "memory");
}
__device__ __forceinline__ void wait_lgkm0() {
    asm volatile("s_waitcnt lgkmcnt(0)" ::: "memory");
    __builtin_amdgcn_sched_barrier(0);
}
__device__ __forceinline__ void barrier_() {
    asm volatile("s_barrier" ::: "memory");
}

__device__ __forceinline__ uint32_t pack4(int4 v) {
    uint32_t r = (uint32_t)(uint8_t)v.x;
    r |= (uint32_t)(uint8_t)v.y << 8;
    r |= (uint32_t)(uint8_t)v.z << 16;
    r |= (uint32_t)(uint8_t)v.w << 24;
    return r;
}

// int32 -> int8 pack (truncate low byte; values already int8-range)
__global__ void convert_kernel(const int* __restrict__ src, int8_t* __restrict__ dst,
                               int n4) {
    int idx = blockIdx.x * blockDim.x + threadIdx.x;
    int stride = gridDim.x * blockDim.x;
    for (int i = idx; i < n4; i += stride) {
        int4 v = ((const int4*)src)[i];
        ((uint32_t*)dst)[i] = pack4(v);
    }
}

#define MFMA_I8 __builtin_amdgcn_mfma_i32_16x16x64_i8

// ---------------------------------------------------------------------------
// gateup: tile 128x128, BK=64B. 8 waves, wave-specialized (G-waves / U-waves,
// each 64x64, acc=64 regs, 4 waves/SIMD). A staged via LDS (2x8KB, proven
// XOR swizzle, counted vmcnt(5), 2-iter DMA lead); B (weights, L2-hot) loaded
// DIRECT global->VGPR with 1-iter register double-buffer -- LDS traffic cut
// from 88KB to 40KB per block-iter (was the 69%-busy top pipe in R10).
// Epilogue: U->G exchange via LDS, SwiGLU+requant.
// ---------------------------------------------------------------------------
__global__ __launch_bounds__(512, 4)
void gateup_kernel(const int8_t* __restrict__ x8, const int8_t* __restrict__ gw8,
                   const int8_t* __restrict__ uw8,
                   const float* __restrict__ galpha, const float* __restrict__ gbias,
                   const float* __restrict__ ualpha, const float* __restrict__ ubias,
                   const float* __restrict__ scale_p, int8_t* __restrict__ hq)
{
    __shared__ __align__(16) int8_t smem_s[32768];
    int8_t* lsA = smem_s;            // 2 bufs x 8KB (pipeline); full 32KB reused for exchange

    const int bid = blockIdx.x;
    const int mt = bid & 31;         // M fastest: 32 blocks share each weight panel in L2
    const int nt = bid >> 5;
    const int m0 = mt << 7;
    const int n0 = nt << 7;

    const int tid  = threadIdx.x;
    const int lane = tid & 63;
    const int wid  = tid >> 6;       // 0..7
    const int isU  = wid >> 2;       // 0: G-wave, 1: U-wave
    const int w4   = wid & 3;
    const int wr   = w4 >> 1;        // 0..1  (M half)
    const int wc   = w4 & 1;         // 0..1  (N half)
    const int lr   = lane & 15;
    const int rdsw = ((lane >> 4) ^ ((lr >> 1) & 3)) << 4;  // proven swizzle

    const int srow = tid >> 2;                           // 0..127
    const int scol = ((tid & 3) ^ ((tid >> 3) & 3)) << 4;
    const int woff = wid << 10;

    const int8_t* As = x8 + (size_t)(m0 + srow) * H_DIM + scol;
    // direct-B per-lane base: row = n0 + wc*64 + lr (+nf*16), 16B chunk by lane>>4
    const int8_t* Bsel = isU ? uw8 : gw8;
    const int8_t* Bp = Bsel + (size_t)(n0 + wc * 64 + lr) * H_DIM + ((lane >> 4) << 4);

    i32x4 acc[4][4];
#pragma unroll
    for (int mf = 0; mf < 4; ++mf)
#pragma unroll
        for (int nf = 0; nf < 4; ++nf) acc[mf][nf] = i32x4{0, 0, 0, 0};

    const int aro = (wr * 64 + lr) * 64 + rdsw;    // + mf*1024

#define STAGE_A(b, kb) gload_lds16(As + (kb), lsA + (b) * 8192 + woff)
#define BLOAD(BF, kb) do { \
        _Pragma("unroll") for (int nf = 0; nf < 4; ++nf) \
            BF[nf] = *(const i32x4*)(Bp + (size_t)nf * 16 * H_DIM + (kb)); \
    } while (0)

#define ITER_GU(tt, BF, BFN) do { \
        wait_vmcnt5(); \
        barrier_(); \
        i32x4 af[4]; \
        _Pragma("unroll") for (int mf = 0; mf < 4; ++mf) \
            af[mf] = *(const i32x4*)(lsA + ((tt) & 1) * 8192 + aro + mf * 1024); \
        wait_lgkm0(); \
        barrier_(); \
        BLOAD(BFN, (((tt) + 1) & (NKT - 1)) << 6); \
        STAGE_A((tt) & 1, (((tt) + 2) & (NKT - 1)) << 6); \
        _Pragma("unroll") for (int mf = 0; mf < 4; ++mf) \
        _Pragma("unroll") for (int nf = 0; nf < 4; ++nf) \
            acc[mf][nf] = MFMA_I8(af[mf], BF[nf], acc[mf][nf], 0, 0, 0); \
    } while (0)

    const int NKT = H_DIM / 64;      // 64 (power of 2)
    i32x4 bfA[4], bfB[4];
    STAGE_A(0, 0);
    BLOAD(bfA, 0);
    STAGE_A(1, 64);
    // vm queue at iter0: [A0, B0x4, A1] -> wait_vmcnt(5) certifies A0. Uniform.

    for (int t = 0; t < NKT; t += 2) {
        ITER_GU(t, bfA, bfB);
        ITER_GU(t + 1, bfB, bfA);
    }
#undef ITER_GU
#undef BLOAD
#undef STAGE_A
    wait_vmcnt0();                   // drain tail prefetches
    barrier_();                      // LDS reusable for exchange

    // ---- exchange U-acc -> G-waves, SwiGLU epilogue (two halves) ----
    const float scale = *scale_p;
#pragma unroll
    for (int h = 0; h < 2; ++h) {
        if (isU) {
#pragma unroll
            for (int mf = 0; mf < 4; ++mf)
#pragma unroll
                for (int q = 0; q < 2; ++q)
                    *(i32x4*)(smem_s + w4 * 8192 + mf * 2048 + q * 1024 + lane * 16)
                        = acc[mf][h * 2 + q];
        }
        barrier_();
        if (!isU) {
#pragma unroll
            for (int q = 0; q < 2; ++q) {
                const int nf = h * 2 + q;
                const int col = n0 + wc * 64 + nf * 16 + lr;
                const float gA = galpha[col], gB = gbias[col];
                const float uA = ualpha[col], uB = ubias[col];
#pragma unroll
                for (int mf = 0; mf < 4; ++mf) {
                    i32x4 uacc = *(const i32x4*)(smem_s + w4 * 8192 + mf * 2048
                                                 + q * 1024 + lane * 16);
                    const int row0 = m0 + wr * 64 + mf * 16 + (lane >> 4) * 4;
#pragma unroll
                    for (int j = 0; j < 4; ++j) {
                        float g = (float)acc[mf][nf][j] * gA + gB;
                        float u = (float)uacc[j] * uA + uB;
                        float s = 1.0f / (1.0f + __expf(-g));
                        float hh = g * s * u;
                        float qv = rintf(hh / scale);
                        qv = fminf(127.0f, fmaxf(-128.0f, qv));
                        hq[(size_t)(row0 + j) * I_DIM + col] = (int8_t)qv;
                    }
                }
            }
        }
        barrier_();
    }
}

// ---------------------------------------------------------------------------
// down: tile 128x256, BK=64B. 8 waves (2M x 4N), wave 64x64 (acc 64).
// A (hq) via LDS (2x8KB); B (dw, L3-resident) direct global->VGPR.
// ---------------------------------------------------------------------------
__global__ __launch_bounds__(512, 4)
void down_kernel(const int8_t* __restrict__ hq, const int8_t* __restrict__ dw8,
                 const float* __restrict__ dalpha, const float* __restrict__ dbias,
                 float* __restrict__ out)
{
    __shared__ __align__(16) int8_t smem_d[16384];
    int8_t* lsA = smem_d;            // 2 bufs x 8KB

    const int bid = blockIdx.x;
    const int mt = bid & 31;         // 32 M tiles of 128 (M fastest: B panel L2-hot)
    const int nt = bid >> 5;         // 16 N tiles of 256
    const int m0 = mt << 7;
    const int n0 = nt << 8;

    const int tid  = threadIdx.x;
    const int lane = tid & 63;
    const int wid  = tid >> 6;
    const int wr   = wid >> 2;       // 0..1
    const int wc   = wid & 3;        // 0..3
    const int lr   = lane & 15;
    const int rdsw = ((lane >> 4) ^ ((lr >> 1) & 3)) << 4;

    const int srow = tid >> 2;
    const int scol = ((tid & 3) ^ ((tid >> 3) & 3)) << 4;
    const int woff = wid << 10;

    const int8_t* Ap = hq + (size_t)(m0 + srow) * I_DIM + scol;
    const int8_t* Bp = dw8 + (size_t)(n0 + wc * 64 + lr) * I_DIM + ((lane >> 4) << 4);

    i32x4 acc[4][4];
#pragma unroll
    for (int mf = 0; mf < 4; ++mf)
#pragma unroll
        for (int nf = 0; nf < 4; ++nf) acc[mf][nf] = i32x4{0, 0, 0, 0};

    const int aro = (wr * 64 + lr) * 64 + rdsw;    // + mf*1024

#define STAGE_A(b, kb) gload_lds16(Ap + (kb), lsA + (b) * 8192 + woff)
#define BLOAD(BF, kb) do { \
        _Pragma("unroll") for (int nf = 0; nf < 4; ++nf) \
            BF[nf] = *(const i32x4*)(Bp + (size_t)nf * 16 * I_DIM + (kb)); \
    } while (0)

#define ITER_D(tt, BF, BFN) do { \
        wait_vmcnt5(); \
        barrier_(); \
        i32x4 af[4]; \
        _Pragma("unroll") for (int mf = 0; mf < 4; ++mf) \
            af[mf] = *(const i32x4*)(lsA + ((tt) & 1) * 8192 + aro + mf * 1024); \
        wait_lgkm0(); \
        barrier_(); \
        BLOAD(BFN, (size_t)((((tt) + 1) % NKT) * 64)); \
        STAGE_A((tt) & 1, (((tt) + 2) % NKT) * 64); \
        _Pragma("unroll") for (int mf = 0; mf < 4; ++mf) \
        _Pragma("unroll") for (int nf = 0; nf < 4; ++nf) \
            acc[mf][nf] = MFMA_I8(af[mf], BF[nf], acc[mf][nf], 0, 0, 0); \
    } while (0)

    const int NKT = I_DIM / 64;      // 172 (even)
    i32x4 bfA[4], bfB[4];
    STAGE_A(0, 0);
    BLOAD(bfA, 0);
    STAGE_A(1, 64);

    for (int t = 0; t < NKT; t += 2) {
        ITER_D(t, bfA, bfB);
        ITER_D(t + 1, bfB, bfA);
    }
#undef ITER_D
#undef BLOAD
#undef STAGE_A
    wait_vmcnt0();

    // ---- epilogue: dequant to fp32 ----
#pragma unroll
    for (int nf = 0; nf < 4; ++nf) {
        const int col = n0 + wc * 64 + nf * 16 + lr;
        const float dA = dalpha[col], dB = dbias[col];
#pragma unroll
        for (int mf = 0; mf < 4; ++mf) {
            const int row0 = m0 + wr * 64 + mf * 16 + (lane >> 4) * 4;
#pragma unroll
            for (int j = 0; j < 4; ++j) {
                out[(size_t)(row0 + j) * H_DIM + col] = (float)acc[mf][nf][j] * dA + dB;
            }
        }
    }
}

extern "C" void kernel_launch(void* const* d_in, const int* in_sizes, int n_in,
                              void* d_out, int out_size, void* d_ws, size_t ws_size,
                              hipStream_t stream) {
    const int* x32  = (const int*)d_in[0];
    const int* gw32 = (const int*)d_in[1];
    const int* uw32 = (const int*)d_in[2];
    const int* dw32 = (const int*)d_in[3];
    const float* ga = (const float*)d_in[4];
    const float* gb = (const float*)d_in[5];
    const float* ua = (const float*)d_in[6];
    const float* ub = (const float*)d_in[7];
    const float* da = (const float*)d_in[8];
    const float* db = (const float*)d_in[9];
    const float* sc = (const float*)d_in[10];
    float* out = (float*)d_out;

    const size_t SZ_X8 = (size_t)T_DIM * H_DIM;
    const size_t SZ_W  = (size_t)I_DIM * H_DIM;
    const size_t SZ_HQ = (size_t)T_DIM * I_DIM;

    int8_t* gw8 = (int8_t*)d_ws;              // reused for dw8 later
    int8_t* uw8 = gw8 + SZ_W;
    int8_t* hq  = uw8 + SZ_W;
    int8_t* x8  = hq + SZ_HQ;

    convert_kernel<<<dim3(2048), dim3(256), 0, stream>>>(x32, x8, (int)(SZ_X8 / 4));
    convert_kernel<<<dim3(2048), dim3(256), 0, stream>>>(gw32, gw8, (int)(SZ_W / 4));
    convert_kernel<<<dim3(2048), dim3(256), 0, stream>>>(uw32, uw8, (int)(SZ_W / 4));
    gateup_kernel<<<dim3(32 * 86), dim3(512), 0, stream>>>(
        x8, gw8, uw8, ga, gb, ua, ub, sc, hq);
    int8_t* dw8 = gw8;   // overwrite gate weights (stream-ordered after gateup)
    convert_kernel<<<dim3(2048), dim3(256), 0, stream>>>(dw32, dw8, (int)(SZ_W / 4));
    down_kernel<<<dim3(32 * 16), dim3(512), 0, stream>>>(hq, dw8, da, db, out);
}

// Round 12
// 703.724 us; speedup vs baseline: 1.7844x; 1.7844x over previous
//
#include <hip/hip_runtime.h>
#include <stdint.h>

#define H_DIM 4096
#define I_DIM 11008
#define T_DIM 4096

typedef int i32x4 __attribute__((ext_vector_type(4)));
typedef const void __attribute__((address_space(1))) gvoid_t;
typedef void __attribute__((address_space(3))) svoid_t;

__device__ __forceinline__ void gload_lds16(const void* gsrc, void* ldst) {
    __builtin_amdgcn_global_load_lds((gvoid_t*)gsrc, (svoid_t*)ldst, 16, 0, 0);
}
__device__ __forceinline__ void wait_vmcnt5() {
    asm volatile("s_waitcnt vmcnt(5)" ::: "memory");
}
__device__ __forceinline__ void wait_vmcnt0() {
    asm volatile("s_waitcnt vmcnt(0)" ::: "memory");
}
__device__ __forceinline__ void wait_lgkm0() {
    asm volatile("s_waitcnt lgkmcnt(0)" ::: "memory");
    __builtin_amdgcn_sched_barrier(0);
}
__device__ __forceinline__ void barrier_() {
    asm volatile("s_barrier" ::: "memory");
}

__device__ __forceinline__ uint32_t pack4(int4 v) {
    uint32_t r = (uint32_t)(uint8_t)v.x;
    r |= (uint32_t)(uint8_t)v.y << 8;
    r |= (uint32_t)(uint8_t)v.z << 16;
    r |= (uint32_t)(uint8_t)v.w << 24;
    return r;
}

// int32 -> int8 pack, linear layout (for x8: row-major, LDS-staged)
__global__ void convert_kernel(const int* __restrict__ src, int8_t* __restrict__ dst,
                               int n4) {
    int idx = blockIdx.x * blockDim.x + threadIdx.x;
    int stride = gridDim.x * blockDim.x;
    for (int i = idx; i < n4; i += stride) {
        int4 v = ((const int4*)src)[i];
        ((uint32_t*)dst)[i] = pack4(v);
    }
}

// int32 [N][K] -> int8 MFMA-fragment order:
// fragment f = (n>>4)*(K/64) + (k>>6) is a contiguous 1024B block,
// byte offset within = ((k&63)>>4)*256 + (n&15)*16 + (k&15)
// (i.e. lane = ((k&63)>>4)*16 + (n&15) holds bytes k..k+15 at lane*16).
// Thread mapping: 16 consecutive threads write 256B contiguous; each thread
// reads one full 64B line (4x int4).
__global__ void convert_frag_kernel(const int* __restrict__ src, int8_t* __restrict__ dst,
                                    int nslots, int kdiv16) {
    const int K = kdiv16 << 4;
    int idx = blockIdx.x * blockDim.x + threadIdx.x;
    int stride = gridDim.x * blockDim.x;
    for (int s = idx; s < nslots; s += stride) {
        const int n_lo = s & 15;
        const int srem = s >> 4;
        const int ks = srem % kdiv16;           // k0 = ks*16
        const int nb = srem / kdiv16;           // n = nb*16 + n_lo
        const int4* p = (const int4*)(src + (size_t)(nb * 16 + n_lo) * K + ks * 16);
        uint4 w;
        w.x = pack4(p[0]); w.y = pack4(p[1]); w.z = pack4(p[2]); w.w = pack4(p[3]);
        const size_t doff = ((size_t)nb * (kdiv16 >> 2) + (ks >> 2)) * 1024
                          + (size_t)(ks & 3) * 256 + (size_t)n_lo * 16;
        *(uint4*)(dst + doff) = w;
    }
}

#define MFMA_I8 __builtin_amdgcn_mfma_i32_16x16x64_i8

// ---------------------------------------------------------------------------
// gateup: tile 128x128, BK=64B. 8 waves, wave-specialized (G-waves / U-waves,
// each 64x64, acc=64 regs, 4 waves/SIMD). A staged via LDS (2x8KB, proven XOR
// swizzle, counted vmcnt(5), 2-iter DMA lead). B in FRAGMENT-ORDERED layout:
// each B-fragment load = one global_load_dwordx4, 64 lanes contiguous (1KB
// burst) from L2/L3-hot weights. LDS/block-iter: 40KB (was 88KB in R10).
// Epilogue: U->G exchange via LDS, SwiGLU+requant.
// ---------------------------------------------------------------------------
__global__ __launch_bounds__(512, 4)
void gateup_kernel(const int8_t* __restrict__ x8, const int8_t* __restrict__ gwf,
                   const int8_t* __restrict__ uwf,
                   const float* __restrict__ galpha, const float* __restrict__ gbias,
                   const float* __restrict__ ualpha, const float* __restrict__ ubias,
                   const float* __restrict__ scale_p, int8_t* __restrict__ hq)
{
    __shared__ __align__(16) int8_t smem_s[32768];
    int8_t* lsA = smem_s;            // 2 bufs x 8KB; full 32KB reused for exchange

    const int bid = blockIdx.x;
    const int mt = bid & 31;         // M fastest: 32 blocks share each weight panel
    const int nt = bid >> 5;
    const int m0 = mt << 7;
    const int n0 = nt << 7;

    const int tid  = threadIdx.x;
    const int lane = tid & 63;
    const int wid  = tid >> 6;       // 0..7
    const int isU  = wid >> 2;       // 0: G-wave, 1: U-wave
    const int w4   = wid & 3;
    const int wr   = w4 >> 1;        // 0..1  (M half)
    const int wc   = w4 & 1;         // 0..1  (N half)
    const int lr   = lane & 15;
    const int rdsw = ((lane >> 4) ^ ((lr >> 1) & 3)) << 4;  // proven swizzle

    const int srow = tid >> 2;                           // 0..127
    const int scol = ((tid & 3) ^ ((tid >> 3) & 3)) << 4;
    const int woff = wid << 10;

    const int8_t* As = x8 + (size_t)(m0 + srow) * H_DIM + scol;
    // fragment-ordered B: frag (ntile16, kblk64) at ((ntile16)*(K/64)+kblk)*1024
    const int KB64 = H_DIM >> 6;     // 64
    const int8_t* Bsel = isU ? uwf : gwf;
    const int8_t* Bq = Bsel + ((size_t)((n0 >> 4) + wc * 4) * KB64) * 1024 + lane * 16;

    i32x4 acc[4][4];
#pragma unroll
    for (int mf = 0; mf < 4; ++mf)
#pragma unroll
        for (int nf = 0; nf < 4; ++nf) acc[mf][nf] = i32x4{0, 0, 0, 0};

    const int aro = (wr * 64 + lr) * 64 + rdsw;    // + mf*1024

#define STAGE_A(b, kb) gload_lds16(As + (kb), lsA + (b) * 8192 + woff)
#define BLOAD(BF, tt) do { \
        _Pragma("unroll") for (int nf = 0; nf < 4; ++nf) \
            BF[nf] = *(const i32x4*)(Bq + ((size_t)nf * KB64 + (tt)) * 1024); \
    } while (0)

#define ITER_GU(tt, BF, BFN) do { \
        wait_vmcnt5(); \
        barrier_(); \
        i32x4 af[4]; \
        _Pragma("unroll") for (int mf = 0; mf < 4; ++mf) \
            af[mf] = *(const i32x4*)(lsA + ((tt) & 1) * 8192 + aro + mf * 1024); \
        wait_lgkm0(); \
        barrier_(); \
        BLOAD(BFN, (((tt) + 1) & (NKT - 1))); \
        STAGE_A((tt) & 1, (((tt) + 2) & (NKT - 1)) << 6); \
        _Pragma("unroll") for (int mf = 0; mf < 4; ++mf) \
        _Pragma("unroll") for (int nf = 0; nf < 4; ++nf) \
            acc[mf][nf] = MFMA_I8(af[mf], BF[nf], acc[mf][nf], 0, 0, 0); \
    } while (0)

    const int NKT = H_DIM / 64;      // 64 (power of 2)
    i32x4 bfA[4], bfB[4];
    STAGE_A(0, 0);
    BLOAD(bfA, 0);
    STAGE_A(1, 64);
    // vm queue: [A0, B0x4, A1] -> wait_vmcnt5 certifies A0; steady state
    // leaves [B(t)x4, A(t+1)] = 5 in flight. Compiler's auto-waitcnt covers B.

    for (int t = 0; t < NKT; t += 2) {
        ITER_GU(t, bfA, bfB);
        ITER_GU(t + 1, bfB, bfA);
    }
#undef ITER_GU
#undef BLOAD
#undef STAGE_A
    wait_vmcnt0();                   // drain tail prefetches
    barrier_();                      // LDS reusable for exchange

    // ---- exchange U-acc -> G-waves, SwiGLU epilogue (two halves) ----
    const float scale = *scale_p;
#pragma unroll
    for (int h = 0; h < 2; ++h) {
        if (isU) {
#pragma unroll
            for (int mf = 0; mf < 4; ++mf)
#pragma unroll
                for (int q = 0; q < 2; ++q)
                    *(i32x4*)(smem_s + w4 * 8192 + mf * 2048 + q * 1024 + lane * 16)
                        = acc[mf][h * 2 + q];
        }
        barrier_();
        if (!isU) {
#pragma unroll
            for (int q = 0; q < 2; ++q) {
                const int nf = h * 2 + q;
                const int col = n0 + wc * 64 + nf * 16 + lr;
                const float gA = galpha[col], gB = gbias[col];
                const float uA = ualpha[col], uB = ubias[col];
#pragma unroll
                for (int mf = 0; mf < 4; ++mf) {
                    i32x4 uacc = *(const i32x4*)(smem_s + w4 * 8192 + mf * 2048
                                                 + q * 1024 + lane * 16);
                    const int row0 = m0 + wr * 64 + mf * 16 + (lane >> 4) * 4;
#pragma unroll
                    for (int j = 0; j < 4; ++j) {
                        float g = (float)acc[mf][nf][j] * gA + gB;
                        float u = (float)uacc[j] * uA + uB;
                        float s = 1.0f / (1.0f + __expf(-g));
                        float hh = g * s * u;
                        float qv = rintf(hh / scale);
                        qv = fminf(127.0f, fmaxf(-128.0f, qv));
                        hq[(size_t)(row0 + j) * I_DIM + col] = (int8_t)qv;
                    }
                }
            }
        }
        barrier_();
    }
}

// ---------------------------------------------------------------------------
// down: tile 128x256, BK=64B. 8 waves (2M x 4N), wave 64x64 (acc 64).
// A (hq, row-major) via LDS; B (dw, fragment-ordered, L3-resident) direct.
// ---------------------------------------------------------------------------
__global__ __launch_bounds__(512, 4)
void down_kernel(const int8_t* __restrict__ hq, const int8_t* __restrict__ dwf,
                 const float* __restrict__ dalpha, const float* __restrict__ dbias,
                 float* __restrict__ out)
{
    __shared__ __align__(16) int8_t smem_d[16384];
    int8_t* lsA = smem_d;            // 2 bufs x 8KB

    const int bid = blockIdx.x;
    const int mt = bid & 31;         // 32 M tiles of 128 (M fastest)
    const int nt = bid >> 5;         // 16 N tiles of 256
    const int m0 = mt << 7;
    const int n0 = nt << 8;

    const int tid  = threadIdx.x;
    const int lane = tid & 63;
    const int wid  = tid >> 6;
    const int wr   = wid >> 2;       // 0..1
    const int wc   = wid & 3;        // 0..3
    const int lr   = lane & 15;
    const int rdsw = ((lane >> 4) ^ ((lr >> 1) & 3)) << 4;

    const int srow = tid >> 2;
    const int scol = ((tid & 3) ^ ((tid >> 3) & 3)) << 4;
    const int woff = wid << 10;

    const int8_t* Ap = hq + (size_t)(m0 + srow) * I_DIM + scol;
    const int KB64 = I_DIM >> 6;     // 172
    const int8_t* Bq = dwf + ((size_t)((n0 >> 4) + wc * 4) * KB64) * 1024 + lane * 16;

    i32x4 acc[4][4];
#pragma unroll
    for (int mf = 0; mf < 4; ++mf)
#pragma unroll
        for (int nf = 0; nf < 4; ++nf) acc[mf][nf] = i32x4{0, 0, 0, 0};

    const int aro = (wr * 64 + lr) * 64 + rdsw;    // + mf*1024

#define STAGE_A(b, kb) gload_lds16(Ap + (kb), lsA + (b) * 8192 + woff)
#define BLOAD(BF, tt) do { \
        _Pragma("unroll") for (int nf = 0; nf < 4; ++nf) \
            BF[nf] = *(const i32x4*)(Bq + ((size_t)nf * KB64 + (tt)) * 1024); \
    } while (0)

#define ITER_D(tt, BF, BFN) do { \
        wait_vmcnt5(); \
        barrier_(); \
        i32x4 af[4]; \
        _Pragma("unroll") for (int mf = 0; mf < 4; ++mf) \
            af[mf] = *(const i32x4*)(lsA + ((tt) & 1) * 8192 + aro + mf * 1024); \
        wait_lgkm0(); \
        barrier_(); \
        BLOAD(BFN, ((tt) + 1) % NKT); \
        STAGE_A((tt) & 1, (size_t)((((tt) + 2) % NKT) * 64)); \
        _Pragma("unroll") for (int mf = 0; mf < 4; ++mf) \
        _Pragma("unroll") for (int nf = 0; nf < 4; ++nf) \
            acc[mf][nf] = MFMA_I8(af[mf], BF[nf], acc[mf][nf], 0, 0, 0); \
    } while (0)

    const int NKT = I_DIM / 64;      // 172 (even)
    i32x4 bfA[4], bfB[4];
    STAGE_A(0, 0);
    BLOAD(bfA, 0);
    STAGE_A(1, 64);

    for (int t = 0; t < NKT; t += 2) {
        ITER_D(t, bfA, bfB);
        ITER_D(t + 1, bfB, bfA);
    }
#undef ITER_D
#undef BLOAD
#undef STAGE_A
    wait_vmcnt0();

    // ---- epilogue: dequant to fp32 ----
#pragma unroll
    for (int nf = 0; nf < 4; ++nf) {
        const int col = n0 + wc * 64 + nf * 16 + lr;
        const float dA = dalpha[col], dB = dbias[col];
#pragma unroll
        for (int mf = 0; mf < 4; ++mf) {
            const int row0 = m0 + wr * 64 + mf * 16 + (lane >> 4) * 4;
#pragma unroll
            for (int j = 0; j < 4; ++j) {
                out[(size_t)(row0 + j) * H_DIM + col] = (float)acc[mf][nf][j] * dA + dB;
            }
        }
    }
}

extern "C" void kernel_launch(void* const* d_in, const int* in_sizes, int n_in,
                              void* d_out, int out_size, void* d_ws, size_t ws_size,
                              hipStream_t stream) {
    const int* x32  = (const int*)d_in[0];
    const int* gw32 = (const int*)d_in[1];
    const int* uw32 = (const int*)d_in[2];
    const int* dw32 = (const int*)d_in[3];
    const float* ga = (const float*)d_in[4];
    const float* gb = (const float*)d_in[5];
    const float* ua = (const float*)d_in[6];
    const float* ub = (const float*)d_in[7];
    const float* da = (const float*)d_in[8];
    const float* db = (const float*)d_in[9];
    const float* sc = (const float*)d_in[10];
    float* out = (float*)d_out;

    const size_t SZ_X8 = (size_t)T_DIM * H_DIM;
    const size_t SZ_W  = (size_t)I_DIM * H_DIM;
    const size_t SZ_HQ = (size_t)T_DIM * I_DIM;

    int8_t* gwf = (int8_t*)d_ws;              // reused for dwf later
    int8_t* uwf = gwf + SZ_W;
    int8_t* hq  = uwf + SZ_W;
    int8_t* x8  = hq + SZ_HQ;

    convert_kernel<<<dim3(2048), dim3(256), 0, stream>>>(x32, x8, (int)(SZ_X8 / 4));
    convert_frag_kernel<<<dim3(2048), dim3(256), 0, stream>>>(
        gw32, gwf, (int)(SZ_W / 16), H_DIM / 16);
    convert_frag_kernel<<<dim3(2048), dim3(256), 0, stream>>>(
        uw32, uwf, (int)(SZ_W / 16), H_DIM / 16);
    gateup_kernel<<<dim3(32 * 86), dim3(512), 0, stream>>>(
        x8, gwf, uwf, ga, gb, ua, ub, sc, hq);
    int8_t* dwf = gwf;   // overwrite gate weights (stream-ordered after gateup)
    convert_frag_kernel<<<dim3(2048), dim3(256), 0, stream>>>(
        dw32, dwf, (int)(SZ_W / 16), I_DIM / 16);
    down_kernel<<<dim3(32 * 16), dim3(512), 0, stream>>>(hq, dwf, da, db, out);
}